// Round 2
// baseline (276.683 us; speedup 1.0000x reference)
//
#include <hip/hip_runtime.h>
#include <hip/hip_bf16.h>

typedef __attribute__((ext_vector_type(8))) short bf16x8;
typedef __attribute__((ext_vector_type(4))) float f32x4;

// Problem constants
#define SPLITN 32
#define DDIM   256
#define UNITS  256
#define BROWS  4096

// GEMM tile config
#define BM 128
#define BN 128
#define BK 64

static __device__ __forceinline__ ushort f2bf(float f) {
    __hip_bfloat16 h = __float2bfloat16(f);
    return *reinterpret_cast<ushort*>(&h);
}

// ---------------------------------------------------------------------------
// Prep: W[s][d][u] fp32  ->  Wt[s][u][d] bf16   (LDS-tiled transpose+convert)
// grid (4,4,32) x 256 threads, 64x64 tiles
// ---------------------------------------------------------------------------
__global__ __launch_bounds__(256) void wt_prep(const float* __restrict__ W,
                                               ushort* __restrict__ Wt) {
    __shared__ float tile[64][65];   // +1 pad: conflict-free transpose
    const int s  = blockIdx.z;
    const int d0 = blockIdx.y * 64;
    const int u0 = blockIdx.x * 64;
    const int t  = threadIdx.x;

    const float* Ws = W + s * 65536;
    #pragma unroll
    for (int i = 0; i < 4; ++i) {
        int f  = t + i * 256;        // 1024 float4 chunks
        int d  = f >> 4;             // 16 float4 per 64-wide row
        int uq = f & 15;
        f32x4 v = *reinterpret_cast<const f32x4*>(Ws + (d0 + d) * 256 + u0 + uq * 4);
        tile[d][uq * 4 + 0] = v[0];
        tile[d][uq * 4 + 1] = v[1];
        tile[d][uq * 4 + 2] = v[2];
        tile[d][uq * 4 + 3] = v[3];
    }
    __syncthreads();

    ushort* Wts = Wt + s * 65536;
    #pragma unroll
    for (int i = 0; i < 4; ++i) {
        int g  = t + i * 256;
        int u  = g >> 4;
        int dq = g & 15;
        uint lo = (uint)f2bf(tile[dq * 4 + 0][u]) | ((uint)f2bf(tile[dq * 4 + 1][u]) << 16);
        uint hi = (uint)f2bf(tile[dq * 4 + 2][u]) | ((uint)f2bf(tile[dq * 4 + 3][u]) << 16);
        uint2 val; val.x = lo; val.y = hi;
        *reinterpret_cast<uint2*>(Wts + (u0 + u) * 256 + d0 + dq * 4) = val;
    }
}

// ---------------------------------------------------------------------------
// Main GEMM: per split s, out[:, s, :] = relu(x[:, s, :] @ W_s + b_s)
// 2048 blocks (XCD-swizzled), 256 threads = 4 waves, 128x128 tile, BK=64.
// bf16 MFMA 16x16x32, fp32 accum. LDS tiles XOR-swizzled (T2).
// ---------------------------------------------------------------------------
__global__ __launch_bounds__(256) void lc_gemm(const float* __restrict__ x,
                                               const ushort* __restrict__ Wt,
                                               const float* __restrict__ bias,
                                               float* __restrict__ out) {
    // bijective XCD swizzle: 2048 % 8 == 0
    const int bid = blockIdx.x;
    const int swz = (bid & 7) * 256 + (bid >> 3);
    const int s   = swz >> 6;          // 64 blocks per split
    const int r   = swz & 63;
    const int mt  = r >> 1;            // 32 M-tiles
    const int nt  = r & 1;             // 2 N-tiles
    const int m0  = mt * BM;
    const int u0  = nt * BN;

    __shared__ ushort As[BM * BK];     // [m][k], XOR-swizzled, 16 KiB
    __shared__ ushort Bs[BN * BK];     // [u][d], XOR-swizzled, 16 KiB

    const int t  = threadIdx.x;
    const int w  = t >> 6, l = t & 63;
    const int wr = w >> 1, wc = w & 1; // wave -> 64x64 sub-tile
    const int lr = l & 15, lg = l >> 4;

    f32x4 acc[4][4];
    #pragma unroll
    for (int i = 0; i < 4; ++i)
        #pragma unroll
        for (int j = 0; j < 4; ++j) {
            f32x4 z = {0.f, 0.f, 0.f, 0.f};
            acc[i][j] = z;
        }

    const float*  xA = x  + (long)m0 * 8192 + s * 256;   // x[m0+m][s][*]
    const ushort* WB = Wt + s * 65536 + u0 * 256;        // Wt[s][u0+u][*]

    for (int kt = 0; kt < 4; ++kt) {
        const int k0 = kt * BK;

        // ---- stage A: 128x64 fp32 -> bf16 (reg-staged convert) ----
        #pragma unroll
        for (int i = 0; i < 8; ++i) {
            int f  = t + i * 256;            // 2048 float4 chunks
            int m  = f >> 4;                 // 16 float4 per row
            int kq = f & 15;
            f32x4 v = *reinterpret_cast<const f32x4*>(xA + m * 8192 + k0 + kq * 4);
            uint lo = (uint)f2bf(v[0]) | ((uint)f2bf(v[1]) << 16);
            uint hi = (uint)f2bf(v[2]) | ((uint)f2bf(v[3]) << 16);
            int e = (m * BK + kq * 4) ^ ((m & 7) << 3);  // T2 XOR swizzle
            uint2 val; val.x = lo; val.y = hi;
            *reinterpret_cast<uint2*>(&As[e]) = val;
        }
        // ---- stage B: 128x64 bf16 straight copy ----
        #pragma unroll
        for (int i = 0; i < 4; ++i) {
            int f  = t + i * 256;            // 1024 16B chunks
            int u  = f >> 3;                 // 8 chunks per row
            int dq = f & 7;
            int4 v = *reinterpret_cast<const int4*>(WB + u * 256 + k0 + dq * 8);
            int e = (u * BK + dq * 8) ^ ((u & 7) << 3);
            *reinterpret_cast<int4*>(&Bs[e]) = v;
        }
        __syncthreads();

        // ---- MFMA: 2 k-halves x 4x4 fragments ----
        #pragma unroll
        for (int kk = 0; kk < BK; kk += 32) {
            bf16x8 af[4], bf[4];
            #pragma unroll
            for (int mi = 0; mi < 4; ++mi) {
                int row = wr * 64 + mi * 16 + lr;
                int e = (row * BK + kk + lg * 8) ^ ((row & 7) << 3);
                af[mi] = *reinterpret_cast<const bf16x8*>(&As[e]);
            }
            #pragma unroll
            for (int ni = 0; ni < 4; ++ni) {
                int row = wc * 64 + ni * 16 + lr;
                int e = (row * BK + kk + lg * 8) ^ ((row & 7) << 3);
                bf[ni] = *reinterpret_cast<const bf16x8*>(&Bs[e]);
            }
            #pragma unroll
            for (int mi = 0; mi < 4; ++mi)
                #pragma unroll
                for (int ni = 0; ni < 4; ++ni)
                    acc[mi][ni] = __builtin_amdgcn_mfma_f32_16x16x32_bf16(
                        af[mi], bf[ni], acc[mi][ni], 0, 0, 0);
        }
        __syncthreads();
    }

    // ---- epilogue: bias + relu, fp32 stores ----
    // C/D layout (verified m89/m91): col = lane&15, row = (lane>>4)*4 + reg
    #pragma unroll
    for (int ni = 0; ni < 4; ++ni) {
        int col = u0 + wc * 64 + ni * 16 + lr;
        float bv = bias[s * 256 + col];
        #pragma unroll
        for (int mi = 0; mi < 4; ++mi) {
            int row0 = m0 + wr * 64 + mi * 16 + lg * 4;
            #pragma unroll
            for (int rr = 0; rr < 4; ++rr) {
                float v = acc[mi][ni][rr] + bv;
                out[(long)(row0 + rr) * 8192 + s * 256 + col] = fmaxf(v, 0.f);
            }
        }
    }
}

// ---------------------------------------------------------------------------
// Fallback (only if workspace is too small for Wt): naive fp32 dot per output
// ---------------------------------------------------------------------------
__global__ void naive_lc(const float* __restrict__ x, const float* __restrict__ W,
                         const float* __restrict__ b, float* __restrict__ out,
                         int total) {
    int i = blockIdx.x * blockDim.x + threadIdx.x;
    if (i >= total) return;
    int u = i & 255;
    int s = (i >> 8) & 31;
    int bi = i >> 13;
    const float* xr = x + (long)bi * 8192 + s * 256;
    const float* wc = W + s * 65536 + u;
    float acc = 0.f;
    #pragma unroll 4
    for (int d = 0; d < 256; ++d) acc += xr[d] * wc[d * 256];
    out[i] = fmaxf(acc + b[s * 256 + u], 0.f);
}

extern "C" void kernel_launch(void* const* d_in, const int* in_sizes, int n_in,
                              void* d_out, int out_size, void* d_ws, size_t ws_size,
                              hipStream_t stream) {
    const float* x = (const float*)d_in[0];
    const float* W = (const float*)d_in[1];
    const float* b = (const float*)d_in[2];
    float* out = (float*)d_out;

    const size_t wt_bytes = (size_t)SPLITN * DDIM * UNITS * sizeof(ushort); // 4 MiB
    if (ws_size >= wt_bytes) {
        ushort* Wt = (ushort*)d_ws;
        wt_prep<<<dim3(4, 4, 32), 256, 0, stream>>>(W, Wt);
        lc_gemm<<<dim3(2048), 256, 0, stream>>>(x, Wt, b, out);
    } else {
        int total = BROWS * SPLITN * UNITS;
        naive_lc<<<(total + 255) / 256, 256, 0, stream>>>(x, W, b, out, total);
    }
}